// Round 7
// baseline (88.053 us; speedup 1.0000x reference)
//
#include <hip/hip_runtime.h>

// x shape (8, 19, 512, 1024) fp32
#define PH 512
#define PW 1024
#define NPLANES 152
#define TOTAL_ELEMS (152ll * 512 * 1024)   // 79,691,776
#define RROWS 16                           // output rows per thread (occupancy sweet spot: ~60 VGPR)
#define NTILES (PH / RROWS)                // 32
#define NBLOCKS (NPLANES * NTILES)         // 4864 (% 8 == 0)
#define NTHREADS 256
#define NXCD 8

__global__ __launch_bounds__(NTHREADS) void box_loss_fused(
    const float* __restrict__ x, float* __restrict__ out) {
    // XCD-aware swizzle: adjacent tiles (sharing 2 halo rows) stay on the
    // same XCD's L2. NBLOCKS % 8 == 0 -> bijective.
    const int bid = (int)blockIdx.x;
    const int swz = (bid & (NXCD - 1)) * (NBLOCKS / NXCD) + (bid >> 3);

    const int wv    = threadIdx.x;         // 0..255, float4 column
    const int tile  = swz & (NTILES - 1);
    const int plane = swz / NTILES;
    const int h0    = tile * RROWS;
    const int lane  = threadIdx.x & 63;
    const int wid   = threadIdx.x >> 6;    // wave id 0..3

    const float* base = x + ((long long)plane << 19) + (wv << 2);

    // Inter-wave seam exchange (block spans the full 1024-wide row).
    __shared__ float eL[RROWS + 2][4];
    __shared__ float eR[RROWS + 2][4];

    // ---- Load 18 rows (16 + 2 halo), batched for MLP depth. ----
    float4 f[RROWS + 2];
    #pragma unroll
    for (int i = 0; i < RROWS + 2; ++i) {
        const int hh = h0 - 1 + i;
        const int hc = min(max(hh, 0), PH - 1);
        f[i] = *reinterpret_cast<const float4*>(base + (hc << 10));
    }
    #pragma unroll
    for (int i = 0; i < RROWS + 2; ++i) {
        if (lane == 0)  eL[i][wid] = f[i].x;
        if (lane == 63) eR[i][wid] = f[i].w;
    }
    __syncthreads();

    // ---- Horizontal 3-sum per row (shuffle + LDS seams), rolling window. ----
    const float inv9 = 1.f / 9.f;
    float acc = 0.f;
    float4 h0v, h1v;

    #pragma unroll
    for (int i = 0; i < RROWS + 2; ++i) {
        const int hh = h0 - 1 + i;
        const float valid = (hh >= 0 && hh < PH) ? 1.f : 0.f;
        float hl = __shfl_up(f[i].w, 1, 64);
        if (lane == 0)  hl = (wid > 0) ? eR[i][wid - 1] : 0.f;   // image left pad
        float hr = __shfl_down(f[i].x, 1, 64);
        if (lane == 63) hr = (wid < 3) ? eL[i][wid + 1] : 0.f;   // image right pad
        float4 h2v;
        h2v.x = (hl     + f[i].x + f[i].y) * valid;
        h2v.y = (f[i].x + f[i].y + f[i].z) * valid;
        h2v.z = (f[i].y + f[i].z + f[i].w) * valid;
        h2v.w = (f[i].z + f[i].w + hr    ) * valid;

        if (i >= 2) {
            const float4 c = f[i - 1];
            acc += fabsf(c.x - (h0v.x + h1v.x + h2v.x) * inv9);
            acc += fabsf(c.y - (h0v.y + h1v.y + h2v.y) * inv9);
            acc += fabsf(c.z - (h0v.z + h1v.z + h2v.z) * inv9);
            acc += fabsf(c.w - (h0v.w + h1v.w + h2v.w) * inv9);
        }
        h0v = h1v;
        h1v = h2v;
    }

    // ---- Wave tree reduction, then block reduction. ----
    #pragma unroll
    for (int off = 32; off > 0; off >>= 1) acc += __shfl_down(acc, off, 64);

    __shared__ float smem[NTHREADS / 64];
    if (lane == 0) smem[wid] = acc;
    __syncthreads();
    if (threadIdx.x == 0) {
        const float s = smem[0] + smem[1] + smem[2] + smem[3];
        // One plain device-scope fp32 atomic per block (no fences/tickets --
        // R5 showed acquire/release sequences cost ~100ns L2 ops each).
        atomicAdd(out, s * (1.f / (float)TOTAL_ELEMS));
    }
}

extern "C" void kernel_launch(void* const* d_in, const int* in_sizes, int n_in,
                              void* d_out, int out_size, void* d_ws, size_t ws_size,
                              hipStream_t stream) {
    const float* x = (const float*)d_in[0];
    float* out = (float*)d_out;

    hipMemsetAsync(out, 0, sizeof(float), stream);
    box_loss_fused<<<NBLOCKS, NTHREADS, 0, stream>>>(x, out);
}

// Round 8
// 55.720 us; speedup vs baseline: 1.5803x; 1.5803x over previous
//
#include <hip/hip_runtime.h>

// x shape (8, 19, 512, 1024) fp32
#define PH 512
#define PW 1024
#define NPLANES 152
#define TOTAL_ELEMS (152ll * 512 * 1024)   // 79,691,776
#define RROWS 16                           // output rows per thread (60 VGPR sweet spot)
#define NTILES (PH / RROWS)                // 32
#define NBLOCKS (NPLANES * NTILES)         // 4864 (% 8 == 0)
#define NTHREADS 256
#define NXCD 8
#define FINAL_THREADS 1024

__global__ __launch_bounds__(NTHREADS) void box_loss_partial(
    const float* __restrict__ x, float* __restrict__ partial) {
    // XCD-aware swizzle: adjacent tiles (sharing 2 halo rows) stay on the
    // same XCD's L2. NBLOCKS % 8 == 0 -> bijective.
    const int bid = (int)blockIdx.x;
    const int swz = (bid & (NXCD - 1)) * (NBLOCKS / NXCD) + (bid >> 3);

    const int wv    = threadIdx.x;         // 0..255, float4 column
    const int tile  = swz & (NTILES - 1);
    const int plane = swz / NTILES;
    const int h0    = tile * RROWS;
    const int lane  = threadIdx.x & 63;
    const int wid   = threadIdx.x >> 6;    // wave id 0..3

    const float* base = x + ((long long)plane << 19) + (wv << 2);

    // Inter-wave seam exchange (block spans the full 1024-wide row).
    __shared__ float eL[RROWS + 2][4];
    __shared__ float eR[RROWS + 2][4];

    // ---- Load 18 rows (16 + 2 halo), batched for MLP depth. ----
    float4 f[RROWS + 2];
    #pragma unroll
    for (int i = 0; i < RROWS + 2; ++i) {
        const int hh = h0 - 1 + i;
        const int hc = min(max(hh, 0), PH - 1);
        f[i] = *reinterpret_cast<const float4*>(base + (hc << 10));
    }
    #pragma unroll
    for (int i = 0; i < RROWS + 2; ++i) {
        if (lane == 0)  eL[i][wid] = f[i].x;
        if (lane == 63) eR[i][wid] = f[i].w;
    }
    __syncthreads();

    // ---- Horizontal 3-sum per row (shuffle + LDS seams), rolling window. ----
    const float inv9 = 1.f / 9.f;
    float acc = 0.f;
    float4 h0v, h1v;

    #pragma unroll
    for (int i = 0; i < RROWS + 2; ++i) {
        const int hh = h0 - 1 + i;
        const float valid = (hh >= 0 && hh < PH) ? 1.f : 0.f;
        float hl = __shfl_up(f[i].w, 1, 64);
        if (lane == 0)  hl = (wid > 0) ? eR[i][wid - 1] : 0.f;   // image left pad
        float hr = __shfl_down(f[i].x, 1, 64);
        if (lane == 63) hr = (wid < 3) ? eL[i][wid + 1] : 0.f;   // image right pad
        float4 h2v;
        h2v.x = (hl     + f[i].x + f[i].y) * valid;
        h2v.y = (f[i].x + f[i].y + f[i].z) * valid;
        h2v.z = (f[i].y + f[i].z + f[i].w) * valid;
        h2v.w = (f[i].z + f[i].w + hr    ) * valid;

        if (i >= 2) {
            const float4 c = f[i - 1];
            acc += fabsf(c.x - (h0v.x + h1v.x + h2v.x) * inv9);
            acc += fabsf(c.y - (h0v.y + h1v.y + h2v.y) * inv9);
            acc += fabsf(c.z - (h0v.z + h1v.z + h2v.z) * inv9);
            acc += fabsf(c.w - (h0v.w + h1v.w + h2v.w) * inv9);
        }
        h0v = h1v;
        h1v = h2v;
    }

    // ---- Wave tree reduction, then block reduction. ----
    #pragma unroll
    for (int off = 32; off > 0; off >>= 1) acc += __shfl_down(acc, off, 64);

    __shared__ float smem[NTHREADS / 64];
    if (lane == 0) smem[wid] = acc;
    __syncthreads();
    if (threadIdx.x == 0) {
        float s = 0.f;
        #pragma unroll
        for (int i = 0; i < NTHREADS / 64; ++i) s += smem[i];
        partial[blockIdx.x] = s;
    }
}

__global__ __launch_bounds__(FINAL_THREADS) void box_loss_final(
    const float* __restrict__ partial, float* __restrict__ out) {
    // 4864 floats = 1216 float4 loads, grid-stride over 1024 threads.
    const float4* p4 = reinterpret_cast<const float4*>(partial);
    float acc = 0.f;
    for (int i = threadIdx.x; i < NBLOCKS / 4; i += FINAL_THREADS) {
        const float4 v = p4[i];
        acc += (v.x + v.y) + (v.z + v.w);
    }
    #pragma unroll
    for (int off = 32; off > 0; off >>= 1) acc += __shfl_down(acc, off, 64);

    __shared__ float smem[FINAL_THREADS / 64];
    const int lane = threadIdx.x & 63;
    const int wid  = threadIdx.x >> 6;
    if (lane == 0) smem[wid] = acc;
    __syncthreads();
    if (threadIdx.x == 0) {
        float s = 0.f;
        #pragma unroll
        for (int i = 0; i < FINAL_THREADS / 64; ++i) s += smem[i];
        out[0] = s * (1.f / (float)TOTAL_ELEMS);
    }
}

extern "C" void kernel_launch(void* const* d_in, const int* in_sizes, int n_in,
                              void* d_out, int out_size, void* d_ws, size_t ws_size,
                              hipStream_t stream) {
    const float* x = (const float*)d_in[0];
    float* out = (float*)d_out;
    float* partial = (float*)d_ws;   // NBLOCKS floats = 19 KB (16B-aligned base)

    box_loss_partial<<<NBLOCKS, NTHREADS, 0, stream>>>(x, partial);
    box_loss_final<<<1, FINAL_THREADS, 0, stream>>>(partial, out);
}